// Round 4
// baseline (211.148 us; speedup 1.0000x reference)
//
#include <hip/hip_runtime.h>

#define NB    8
#define NQL   2048
#define NKL   2048
#define DD    64
#define DVV   64
#define QT    128            // q rows per block
#define NQT   16             // NQL/QT
#define CHK   512            // keys per chunk (8 steps)
#define MAXCH 4              // NKL/CHK
#define KSTEP 64

typedef __attribute__((ext_vector_type(8))) short bf16x8;
typedef __attribute__((ext_vector_type(4))) short bf16x4;
typedef __attribute__((ext_vector_type(2))) short bf16x2;
typedef __attribute__((ext_vector_type(4))) float f32x4;

#define L2E 1.44269504088896340736f

__device__ __forceinline__ unsigned short f2bf(float x) {
    union { float f; unsigned u; } v; v.f = x;
    unsigned r = v.u + 0x7FFFu + ((v.u >> 16) & 1u);
    return (unsigned short)(r >> 16);
}

// agent-scope coherent load (bypasses stale per-XCD cache lines)
__device__ __forceinline__ float ldc(const float* p) {
    return __hip_atomic_load(p, __ATOMIC_RELAXED, __HIP_MEMORY_SCOPE_AGENT);
}

// LDS swizzles (indices in shorts; rows are 64 shorts = 128 B).
__device__ __forceinline__ int kswz(int row, int col) {
    return row * 64 + (col ^ ((row & 7) << 3));
}
__device__ __forceinline__ int vswz(int dv, int col) {
    return dv * 64 + (col ^ ((((dv & 7) ^ ((dv >> 3) & 7))) << 3));
}

// ============ fused kernel: flash partials + fire-and-combine ============
// grid = NB*NQT*MAXCH. block (b, qt, kc): 128 q-rows x 512 keys.
// 4 waves q-split (32 rows each = 2 sub-tiles of 16). K/V staged fp32->bf16
// in LDS per 64-key step, double-buffered. Last finishing chunk of a q-tile
// combines all partials (device-scope atomics + agent-coherent loads).
__global__ __launch_bounds__(256, 4)
void attn_fused(const float* __restrict__ Qg, const float* __restrict__ Kg,
                const float* __restrict__ Vg, float* __restrict__ Og,
                float* __restrict__ ws)
{
    int*   cnt = (int*)ws;
    float* Mp  = ws + 256;
    float* Lp  = Mp + (size_t)(NB * NQT) * MAXCH * QT;
    float* Op  = Lp + (size_t)(NB * NQT) * MAXCH * QT;

    const int bid = blockIdx.x;
    const int kc  = bid & 3;
    const int qt  = (bid >> 2) & 15;
    const int b   = bid >> 6;
    const int nkeys = QT * (qt + 1);
    const int KC0   = kc * CHK;
    if (KC0 >= nkeys) return;
    const int nsteps = min(8, (nkeys - KC0) >> 6);
    const int nch    = (qt + 4) >> 2;          // ceil((qt+1)/4)
    const int tile   = b * NQT + qt;

    const int tid  = threadIdx.x;
    const int wv   = tid >> 6;
    const int lane = tid & 63;
    const int c    = lane & 15;
    const int h    = lane >> 4;
    const int Q0   = qt * QT;
    const int R0l  = 32 * wv;                  // wave's local row base

    const float* Qb = Qg + (size_t)b * NQL * DD;
    const float* Kb = Kg + (size_t)b * NKL * DD;
    const float* Vb = Vg + (size_t)b * NKL * DVV;

    // LDS union: staging (32 KB) overlapped by Ot (34.8 KB) after the loop.
    __shared__ __align__(16) char smem[38416];
    short (*Kl)[4096] = (short (*)[4096])smem;
    short (*Vl)[4096] = (short (*)[4096])(smem + 16384);
    float (*Ot)[68]   = (float (*)[68])smem;
    float* Mr   = (float*)(smem + 34816);
    float* Lr   = Mr + 128;
    float* scb  = Lr + 128;                    // [4][128]
    float* invb = scb + 512;
    int*   flg  = (int*)(invb + 128);

    // staging maps (identical to verified round-3 scheme)
    const int skr = tid >> 2;
    const int sdc = (tid & 3) * 16;
    const int vkr = (tid >> 3) << 1;
    const int vdc = (tid & 7) * 8;
    f32x4 kr[4], vr[4];

    // Q fragments (B-operand), 1/8 folded. qf[qs][dh] slot (h,j) = Q[row][dh*32+8h+j]
    bf16x8 qf[2][2];
#pragma unroll
    for (int qs = 0; qs < 2; ++qs)
#pragma unroll
        for (int dh = 0; dh < 2; ++dh) {
            const float* src = Qb + (size_t)(Q0 + R0l + 16 * qs + c) * DD + dh * 32 + h * 8;
            f32x4 x0 = *(const f32x4*)(src);
            f32x4 x1 = *(const f32x4*)(src + 4);
            bf16x8 t;
#pragma unroll
            for (int j = 0; j < 4; ++j) {
                t[j]     = (short)f2bf(x0[j] * 0.125f);
                t[4 + j] = (short)f2bf(x1[j] * 0.125f);
            }
            qf[qs][dh] = t;
        }

    // prologue: stage step 0
    {
        const float* kb0 = Kb + (size_t)(KC0 + skr) * DD + sdc;
        kr[0] = *(const f32x4*)(kb0);     kr[1] = *(const f32x4*)(kb0 + 4);
        kr[2] = *(const f32x4*)(kb0 + 8); kr[3] = *(const f32x4*)(kb0 + 12);
        const float* vb0 = Vb + (size_t)(KC0 + vkr) * DVV + vdc;
        vr[0] = *(const f32x4*)(vb0);       vr[1] = *(const f32x4*)(vb0 + 4);
        vr[2] = *(const f32x4*)(vb0 + DVV); vr[3] = *(const f32x4*)(vb0 + DVV + 4);
        short* Kd = Kl[0]; short* Vd = Vl[0];
#pragma unroll
        for (int i = 0; i < 4; ++i) {
            bf16x4 t;
#pragma unroll
            for (int j = 0; j < 4; ++j) t[j] = (short)f2bf(kr[i][j]);
            *(bf16x4*)(Kd + kswz(skr, sdc + 4 * i)) = t;
        }
#pragma unroll
        for (int j = 0; j < 8; ++j) {
            bf16x2 t;
            t[0] = (short)f2bf(vr[j >> 2][j & 3]);
            t[1] = (short)f2bf(vr[2 + (j >> 2)][j & 3]);
            *(bf16x2*)(Vd + vswz(vdc + j, vkr)) = t;
        }
    }
    __syncthreads();

    float m[2] = {-INFINITY, -INFINITY};
    float l[2] = {0.f, 0.f};
    f32x4 acc[2][4];
    {
        f32x4 z = {0.f, 0.f, 0.f, 0.f};
#pragma unroll
        for (int qs = 0; qs < 2; ++qs)
#pragma unroll
            for (int s4 = 0; s4 < 4; ++s4) acc[qs][s4] = z;
    }

    for (int s = 0; s < nsteps; ++s) {
        const int pb = s & 1;

        if (s + 1 < nsteps) {   // T14: issue next step's global loads early
            const float* kb0 = Kb + (size_t)(KC0 + (s + 1) * KSTEP + skr) * DD + sdc;
            kr[0] = *(const f32x4*)(kb0);     kr[1] = *(const f32x4*)(kb0 + 4);
            kr[2] = *(const f32x4*)(kb0 + 8); kr[3] = *(const f32x4*)(kb0 + 12);
            const float* vb0 = Vb + (size_t)(KC0 + (s + 1) * KSTEP + vkr) * DVV + vdc;
            vr[0] = *(const f32x4*)(vb0);       vr[1] = *(const f32x4*)(vb0 + 4);
            vr[2] = *(const f32x4*)(vb0 + DVV); vr[3] = *(const f32x4*)(vb0 + DVV + 4);
        }

        const int kg0 = KC0 + s * KSTEP;
        if (kg0 <= Q0 + R0l + 31) {            // wave-active (wave-uniform)
            const short* Kd = Kl[pb];
            const short* Vd = Vl[pb];
#pragma unroll
            for (int qs = 0; qs < 2; ++qs) {
                f32x4 st[4];
                {
                    f32x4 z = {0.f, 0.f, 0.f, 0.f};
#pragma unroll
                    for (int t = 0; t < 4; ++t) st[t] = z;
                }
#pragma unroll
                for (int t = 0; t < 4; ++t)
#pragma unroll
                    for (int dh = 0; dh < 2; ++dh) {
                        bf16x8 kf = *(const bf16x8*)(Kd + kswz(16 * t + c, dh * 32 + h * 8));
                        st[t] = __builtin_amdgcn_mfma_f32_16x16x32_bf16(kf, qf[qs][dh], st[t], 0, 0, 0);
                    }

                if (kg0 + KSTEP - 1 > Q0 + R0l + 16 * qs) {   // diagonal step
                    const int qg = Q0 + R0l + 16 * qs + c;
#pragma unroll
                    for (int t = 0; t < 4; ++t)
#pragma unroll
                        for (int r = 0; r < 4; ++r) {
                            int key = kg0 + 16 * t + 4 * h + r;
                            if (key > qg) st[t][r] = -1e9f;
                        }
                }

                float vmax = st[0][0];
#pragma unroll
                for (int t = 0; t < 4; ++t)
#pragma unroll
                    for (int r = 0; r < 4; ++r) vmax = fmaxf(vmax, st[t][r]);
                vmax = fmaxf(vmax, __shfl_xor(vmax, 16));
                vmax = fmaxf(vmax, __shfl_xor(vmax, 32));

                if (!__all(vmax - m[qs] <= 8.0f)) {
                    float mn    = fmaxf(m[qs], vmax);
                    float alpha = exp2f((m[qs] - mn) * L2E);
                    l[qs] *= alpha;
#pragma unroll
                    for (int s4 = 0; s4 < 4; ++s4)
#pragma unroll
                        for (int r = 0; r < 4; ++r) acc[qs][s4][r] *= alpha;
                    m[qs] = mn;
                }

                float p[4][4];
                float ps = 0.f;
#pragma unroll
                for (int t = 0; t < 4; ++t)
#pragma unroll
                    for (int r = 0; r < 4; ++r) {
                        p[t][r] = exp2f((st[t][r] - m[qs]) * L2E);
                        ps += p[t][r];
                    }
                ps += __shfl_xor(ps, 16);
                ps += __shfl_xor(ps, 32);
                l[qs] += ps;

                bf16x8 pf[2];
#pragma unroll
                for (int u = 0; u < 2; ++u) {
                    bf16x8 t;
#pragma unroll
                    for (int j = 0; j < 8; ++j) t[j] = (short)f2bf(p[2 * u + (j >> 2)][j & 3]);
                    pf[u] = t;
                }
#pragma unroll
                for (int s4 = 0; s4 < 4; ++s4)
#pragma unroll
                    for (int u = 0; u < 2; ++u) {
                        bf16x4 lo = *(const bf16x4*)(Vd + vswz(c + 16 * s4, 32 * u + 4 * h));
                        bf16x4 hi = *(const bf16x4*)(Vd + vswz(c + 16 * s4, 32 * u + 16 + 4 * h));
                        bf16x8 vf = {lo[0], lo[1], lo[2], lo[3], hi[0], hi[1], hi[2], hi[3]};
                        acc[qs][s4] = __builtin_amdgcn_mfma_f32_16x16x32_bf16(vf, pf[u], acc[qs][s4], 0, 0, 0);
                    }
            }
        }

        if (s + 1 < nsteps) {   // write next step into the other buffer
            short* Kd = Kl[(s + 1) & 1];
            short* Vd = Vl[(s + 1) & 1];
#pragma unroll
            for (int i = 0; i < 4; ++i) {
                bf16x4 t;
#pragma unroll
                for (int j = 0; j < 4; ++j) t[j] = (short)f2bf(kr[i][j]);
                *(bf16x4*)(Kd + kswz(skr, sdc + 4 * i)) = t;
            }
#pragma unroll
            for (int j = 0; j < 8; ++j) {
                bf16x2 t;
                t[0] = (short)f2bf(vr[j >> 2][j & 3]);
                t[1] = (short)f2bf(vr[2 + (j >> 2)][j & 3]);
                *(bf16x2*)(Vd + vswz(vdc + j, vkr)) = t;
            }
        }
        __syncthreads();
    }

    // ---- epilogue: acc -> LDS (overlaps staging buffers; all compute done)
#pragma unroll
    for (int qs = 0; qs < 2; ++qs) {
        if (h == 0) {
            Mr[R0l + 16 * qs + c] = m[qs];
            Lr[R0l + 16 * qs + c] = l[qs];
        }
#pragma unroll
        for (int s4 = 0; s4 < 4; ++s4)
            *(f32x4*)&Ot[R0l + 16 * qs + c][16 * s4 + 4 * h] = acc[qs][s4];
    }
    __syncthreads();

    float* Ogb = Og + ((size_t)b * NQL + Q0) * DVV;

    if (nch == 1) {   // single-chunk tile: finalize directly
        if (tid < 128) invb[tid] = 1.0f / Lr[tid];
        __syncthreads();
#pragma unroll
        for (int j = 0; j < 32; ++j) {
            int f = j * 256 + tid;
            Ogb[f] = Ot[f >> 6][f & 63] * invb[f >> 6];
        }
        return;
    }

    // ---- partial store (coalesced), then fence + counter
    {
        float* Opg = Op + ((size_t)tile * MAXCH + kc) * (QT * DVV);
#pragma unroll
        for (int j = 0; j < 32; ++j) {
            int f = j * 256 + tid;
            Opg[f] = Ot[f >> 6][f & 63];
        }
        if (tid < 128) {
            Mp[((size_t)tile * MAXCH + kc) * QT + tid] = Mr[tid];
            Lp[((size_t)tile * MAXCH + kc) * QT + tid] = Lr[tid];
        }
    }
    __threadfence();
    __syncthreads();
    if (tid == 0) {
        int old = atomicAdd(cnt + tile, 1);
        *flg = (old == nch - 1) ? 1 : 0;
    }
    __syncthreads();
    if (*flg == 0) return;

    // ---- this block is last for the tile: combine all chunks
    __threadfence();
    if (tid < 128) {
        float mv0 = -INFINITY, mv1 = -INFINITY, mv2 = -INFINITY, mv3 = -INFINITY;
        mv0 = ldc(&Mp[((size_t)tile * MAXCH + 0) * QT + tid]);
        mv1 = ldc(&Mp[((size_t)tile * MAXCH + 1) * QT + tid]);
        if (nch > 2) mv2 = ldc(&Mp[((size_t)tile * MAXCH + 2) * QT + tid]);
        if (nch > 3) mv3 = ldc(&Mp[((size_t)tile * MAXCH + 3) * QT + tid]);
        float M = fmaxf(fmaxf(mv0, mv1), fmaxf(mv2, mv3));
        float e0 = exp2f((mv0 - M) * L2E), e1 = exp2f((mv1 - M) * L2E);
        float e2 = (nch > 2) ? exp2f((mv2 - M) * L2E) : 0.f;
        float e3 = (nch > 3) ? exp2f((mv3 - M) * L2E) : 0.f;
        float den = e0 * ldc(&Lp[((size_t)tile * MAXCH + 0) * QT + tid])
                  + e1 * ldc(&Lp[((size_t)tile * MAXCH + 1) * QT + tid]);
        if (nch > 2) den += e2 * ldc(&Lp[((size_t)tile * MAXCH + 2) * QT + tid]);
        if (nch > 3) den += e3 * ldc(&Lp[((size_t)tile * MAXCH + 3) * QT + tid]);
        float iv = 1.0f / den;
        scb[0 * 128 + tid] = e0 * iv;
        scb[1 * 128 + tid] = e1 * iv;
        scb[2 * 128 + tid] = e2 * iv;
        scb[3 * 128 + tid] = e3 * iv;
    }
    __syncthreads();

    const float* Opt = Op + (size_t)tile * MAXCH * (QT * DVV);
#pragma unroll
    for (int j = 0; j < 32; ++j) {
        int f = j * 256 + tid;
        int q = f >> 6;
        float val = scb[0 * 128 + q] * ldc(&Opt[(size_t)0 * (QT * DVV) + f])
                  + scb[1 * 128 + q] * ldc(&Opt[(size_t)1 * (QT * DVV) + f]);
        if (nch > 2) val += scb[2 * 128 + q] * ldc(&Opt[(size_t)2 * (QT * DVV) + f]);
        if (nch > 3) val += scb[3 * 128 + q] * ldc(&Opt[(size_t)3 * (QT * DVV) + f]);
        Ogb[f] = val;
    }
}

// ================= fallback (no workspace): round-1 kernel =================
__global__ __launch_bounds__(256, 4)
void attn_fwd_fb(const float* __restrict__ Qg, const float* __restrict__ Kg,
                 const float* __restrict__ Vg, float* __restrict__ Og)
{
    const int tid  = threadIdx.x;
    const int wv   = tid >> 6;
    const int lane = tid & 63;
    const int c    = lane & 15;
    const int h    = lane >> 4;
    const int bid = blockIdx.x;
    const int b   = bid & 7;
    const int qt  = bid >> 3;
    const int q0  = qt << 4;
    const float* Qb = Qg + (size_t)b * NQL * DD;
    const float* Kb = Kg + (size_t)b * NKL * DD;
    const float* Vb = Vg + (size_t)b * NKL * DVV;
    bf16x8 qf[2];
#pragma unroll
    for (int dh = 0; dh < 2; ++dh) {
        const float* src = Qb + (size_t)(q0 + c) * DD + dh * 32 + h * 8;
        f32x4 x0 = *(const f32x4*)(src);
        f32x4 x1 = *(const f32x4*)(src + 4);
        bf16x8 t;
#pragma unroll
        for (int j = 0; j < 4; ++j) {
            t[j]     = (short)f2bf(x0[j] * 0.125f);
            t[4 + j] = (short)f2bf(x1[j] * 0.125f);
        }
        qf[dh] = t;
    }
    float m = -INFINITY, l = 0.0f;
    f32x4 acc[4];
    {
        f32x4 z = {0.f, 0.f, 0.f, 0.f};
#pragma unroll
        for (int s = 0; s < 4; ++s) acc[s] = z;
    }
    const int nkt = (q0 + 47) >> 5;
    for (int kt = wv; kt < nkt; kt += 4) {
        const int kb = kt << 5;
        f32x4 st[2];
        {
            f32x4 z = {0.f, 0.f, 0.f, 0.f};
            st[0] = z; st[1] = z;
        }
#pragma unroll
        for (int t = 0; t < 2; ++t)
#pragma unroll
            for (int dh = 0; dh < 2; ++dh) {
                const float* src = Kb + (size_t)(kb + t * 16 + c) * DD + dh * 32 + h * 8;
                f32x4 x0 = *(const f32x4*)(src);
                f32x4 x1 = *(const f32x4*)(src + 4);
                bf16x8 kf;
#pragma unroll
                for (int j = 0; j < 4; ++j) {
                    kf[j]     = (short)f2bf(x0[j]);
                    kf[4 + j] = (short)f2bf(x1[j]);
                }
                st[t] = __builtin_amdgcn_mfma_f32_16x16x32_bf16(kf, qf[dh], st[t], 0, 0, 0);
            }
        if (kb + 31 > q0) {
#pragma unroll
            for (int t = 0; t < 2; ++t)
#pragma unroll
                for (int r = 0; r < 4; ++r) {
                    int key = kb + t * 16 + h * 4 + r;
                    if (key > q0 + c) st[t][r] = -1e9f;
                }
        }
        float vmax = st[0][0];
#pragma unroll
        for (int t = 0; t < 2; ++t)
#pragma unroll
            for (int r = 0; r < 4; ++r) vmax = fmaxf(vmax, st[t][r]);
        vmax = fmaxf(vmax, __shfl_xor(vmax, 16));
        vmax = fmaxf(vmax, __shfl_xor(vmax, 32));
        float mn    = fmaxf(m, vmax);
        float alpha = exp2f((m - mn) * L2E);
        float p[2][4];
        float ps = 0.f;
#pragma unroll
        for (int t = 0; t < 2; ++t)
#pragma unroll
            for (int r = 0; r < 4; ++r) {
                p[t][r] = exp2f((st[t][r] - mn) * L2E);
                ps += p[t][r];
            }
        ps += __shfl_xor(ps, 16);
        ps += __shfl_xor(ps, 32);
        l = l * alpha + ps;
        m = mn;
#pragma unroll
        for (int s = 0; s < 4; ++s)
#pragma unroll
            for (int r = 0; r < 4; ++r) acc[s][r] *= alpha;
        bf16x8 pf;
#pragma unroll
        for (int j = 0; j < 8; ++j) pf[j] = (short)f2bf(p[j >> 2][j & 3]);
        size_t vrow[8];
#pragma unroll
        for (int j = 0; j < 8; ++j)
            vrow[j] = (size_t)(kb + h * 4 + (j & 3) + ((j >> 2) << 4)) * DVV + c;
#pragma unroll
        for (int s = 0; s < 4; ++s) {
            bf16x8 vf;
#pragma unroll
            for (int j = 0; j < 8; ++j) vf[j] = (short)f2bf(Vb[vrow[j] + s * 16]);
            acc[s] = __builtin_amdgcn_mfma_f32_16x16x32_bf16(vf, pf, acc[s], 0, 0, 0);
        }
    }
    __shared__ float Osc[4][64][17];
    __shared__ float Msc[4][16];
    __shared__ float Lsc[4][16];
#pragma unroll
    for (int s = 0; s < 4; ++s)
#pragma unroll
        for (int r = 0; r < 4; ++r)
            Osc[wv][s * 16 + h * 4 + r][c] = acc[s][r];
    if (lane < 16) { Msc[wv][c] = m; Lsc[wv][c] = l; }
    __syncthreads();
#pragma unroll
    for (int ri = 0; ri < 4; ++ri) {
        const int q = wv * 4 + ri;
        float M = fmaxf(fmaxf(Msc[0][q], Msc[1][q]), fmaxf(Msc[2][q], Msc[3][q]));
        float val = 0.f, den = 0.f;
#pragma unroll
        for (int w2 = 0; w2 < 4; ++w2) {
            float sc = exp2f((Msc[w2][q] - M) * L2E);
            den += Lsc[w2][q] * sc;
            val += Osc[w2][lane][q] * sc;
        }
        Og[((size_t)b * NQL + q0 + q) * DVV + lane] = val / den;
    }
}

extern "C" void kernel_launch(void* const* d_in, const int* in_sizes, int n_in,
                              void* d_out, int out_size, void* d_ws, size_t ws_size,
                              hipStream_t stream)
{
    (void)in_sizes; (void)n_in; (void)out_size;
    const float* Q = (const float*)d_in[0];
    const float* K = (const float*)d_in[1];
    const float* V = (const float*)d_in[2];
    float* O = (float*)d_out;

    // ws layout (floats): cnt 256 | Mp 128*4*128 | Lp 128*4*128 | Op 128*4*128*64
    const size_t need_f = 256 + 2 * (size_t)(NB * NQT) * MAXCH * QT
                        + (size_t)(NB * NQT) * MAXCH * QT * DVV;
    if (ws_size >= need_f * sizeof(float)) {
        hipMemsetAsync(d_ws, 0, 1024, stream);   // zero the tile counters
        attn_fused<<<dim3(NB * NQT * MAXCH), dim3(256), 0, stream>>>(
            Q, K, V, O, (float*)d_ws);
    } else {
        attn_fwd_fb<<<dim3(NB * (NQL / 16)), dim3(256), 0, stream>>>(Q, K, V, O);
    }
}

// Round 5
// 56.386 us; speedup vs baseline: 3.7447x; 3.7447x over previous
//
#include <hip/hip_runtime.h>

#define NB    8
#define NQL   2048
#define NKL   2048
#define DD    64
#define DVV   64
#define QT    128            // q rows per block (8 waves x 16 rows)
#define NQT   16             // NQL/QT
#define CHK   256            // keys per chunk (4 steps of 64)
#define MAXCH 8              // NKL/CHK
#define KSTEP 64

typedef __attribute__((ext_vector_type(8))) short bf16x8;
typedef __attribute__((ext_vector_type(4))) short bf16x4;
typedef __attribute__((ext_vector_type(2))) short bf16x2;
typedef __attribute__((ext_vector_type(4))) float f32x4;

#define L2E 1.44269504088896340736f

__device__ __forceinline__ unsigned short f2bf(float x) {
    union { float f; unsigned u; } v; v.f = x;
    unsigned r = v.u + 0x7FFFu + ((v.u >> 16) & 1u);
    return (unsigned short)(r >> 16);
}

// LDS swizzles (indices in shorts; rows are 64 shorts = 128 B).
__device__ __forceinline__ int kswz(int row, int col) {
    return row * 64 + (col ^ ((row & 7) << 3));
}
__device__ __forceinline__ int vswz(int dv, int col) {
    return dv * 64 + (col ^ ((((dv & 7) ^ ((dv >> 3) & 7))) << 3));
}

// ================= Phase 1: partial flash attention =================
// grid = NB*NQT*MAXCH; block (b, qt, kc): 128 q-rows x 256 keys.
// 8 waves q-split (16 rows each). K/V staged fp32->bf16 in LDS per 64-key
// step, double-buffered, T14 prefetch. No fences, no atomics.
__global__ __launch_bounds__(512, 4)
void attn_part(const float* __restrict__ Qg, const float* __restrict__ Kg,
               const float* __restrict__ Vg, float* __restrict__ Og,
               float* __restrict__ Mp, float* __restrict__ Lp,
               float* __restrict__ Op)
{
    const int bid = blockIdx.x;
    const int kc  = bid & 7;
    const int qt  = (bid >> 3) & 15;
    const int b   = bid >> 7;
    const int nkeys = QT * (qt + 1);
    const int KC0   = kc * CHK;
    if (KC0 >= nkeys) return;
    const int nsteps = (min(nkeys - KC0, CHK)) >> 6;   // 2 or 4
    const int nch    = (qt + 2) >> 1;                  // ceil((qt+1)/2)
    const int tile   = b * NQT + qt;

    const int tid  = threadIdx.x;
    const int wv   = tid >> 6;          // 0..7
    const int lane = tid & 63;
    const int c    = lane & 15;
    const int h    = lane >> 4;
    const int Q0   = qt * QT;
    const int R0l  = 16 * wv;           // wave's local row base

    const float* Qb = Qg + (size_t)b * NQL * DD;
    const float* Kb = Kg + (size_t)b * NKL * DD;
    const float* Vb = Vg + (size_t)b * NKL * DVV;

    // LDS: staging 32 KB, overlaid by epilogue Ot/Mr/Lr/invb (36.4 KB total)
    __shared__ __align__(16) char smem[36864];
    short (*Kl)[4096] = (short (*)[4096])smem;
    short (*Vl)[4096] = (short (*)[4096])(smem + 16384);
    float (*Ot)[68]   = (float (*)[68])smem;            // [128][68]
    float* Mr   = (float*)(smem + 34816);               // [128]
    float* Lr   = Mr + 128;                             // [128]
    float* invb = Lr + 128;                             // [128]

    // staging maps (512 threads, 8 floats each for K and V)
    const int skr = tid >> 3;            // K row 0..63
    const int sdc = (tid & 7) * 8;       // K col base
    const int vkr = (tid >> 4) << 1;     // V key pair 0..62
    const int vdc = (tid & 15) * 4;      // V dv base 0..60
    f32x4 kr[2], vr[2];

    // Q fragments (B-operand), 1/8 folded. slot (h,j) = Q[row][dh*32+8h+j]
    bf16x8 qf[2];
#pragma unroll
    for (int dh = 0; dh < 2; ++dh) {
        const float* src = Qb + (size_t)(Q0 + R0l + c) * DD + dh * 32 + h * 8;
        f32x4 x0 = *(const f32x4*)(src);
        f32x4 x1 = *(const f32x4*)(src + 4);
        bf16x8 t;
#pragma unroll
        for (int j = 0; j < 4; ++j) {
            t[j]     = (short)f2bf(x0[j] * 0.125f);
            t[4 + j] = (short)f2bf(x1[j] * 0.125f);
        }
        qf[dh] = t;
    }

    // prologue: stage step 0
    {
        const float* kb0 = Kb + (size_t)(KC0 + skr) * DD + sdc;
        kr[0] = *(const f32x4*)(kb0); kr[1] = *(const f32x4*)(kb0 + 4);
        const float* vb0 = Vb + (size_t)(KC0 + vkr) * DVV + vdc;
        vr[0] = *(const f32x4*)(vb0); vr[1] = *(const f32x4*)(vb0 + DVV);
        short* Kd = Kl[0]; short* Vd = Vl[0];
#pragma unroll
        for (int i = 0; i < 2; ++i) {
            bf16x4 t;
#pragma unroll
            for (int j = 0; j < 4; ++j) t[j] = (short)f2bf(kr[i][j]);
            *(bf16x4*)(Kd + kswz(skr, sdc + 4 * i)) = t;
        }
#pragma unroll
        for (int j = 0; j < 4; ++j) {
            bf16x2 t;
            t[0] = (short)f2bf(vr[0][j]);
            t[1] = (short)f2bf(vr[1][j]);
            *(bf16x2*)(Vd + vswz(vdc + j, vkr)) = t;
        }
    }
    __syncthreads();

    float m = -INFINITY, l = 0.0f;
    f32x4 acc[4];
    {
        f32x4 z = {0.f, 0.f, 0.f, 0.f};
#pragma unroll
        for (int s4 = 0; s4 < 4; ++s4) acc[s4] = z;
    }

    for (int s = 0; s < nsteps; ++s) {
        const int pb = s & 1;

        if (s + 1 < nsteps) {   // T14: issue next step's global loads early
            const float* kb0 = Kb + (size_t)(KC0 + (s + 1) * KSTEP + skr) * DD + sdc;
            kr[0] = *(const f32x4*)(kb0); kr[1] = *(const f32x4*)(kb0 + 4);
            const float* vb0 = Vb + (size_t)(KC0 + (s + 1) * KSTEP + vkr) * DVV + vdc;
            vr[0] = *(const f32x4*)(vb0); vr[1] = *(const f32x4*)(vb0 + DVV);
        }

        const int kg0 = KC0 + s * KSTEP;
        if (kg0 <= Q0 + R0l + 15) {        // wave-active (wave-uniform)
            const short* Kd = Kl[pb];
            const short* Vd = Vl[pb];

            f32x4 st[4];
            {
                f32x4 z = {0.f, 0.f, 0.f, 0.f};
#pragma unroll
                for (int t = 0; t < 4; ++t) st[t] = z;
            }
#pragma unroll
            for (int t = 0; t < 4; ++t)
#pragma unroll
                for (int dh = 0; dh < 2; ++dh) {
                    bf16x8 kf = *(const bf16x8*)(Kd + kswz(16 * t + c, dh * 32 + h * 8));
                    st[t] = __builtin_amdgcn_mfma_f32_16x16x32_bf16(kf, qf[dh], st[t], 0, 0, 0);
                }

            if (kg0 + KSTEP - 1 > Q0 + R0l) {   // diagonal step: mask
                const int qg = Q0 + R0l + c;
#pragma unroll
                for (int t = 0; t < 4; ++t)
#pragma unroll
                    for (int r = 0; r < 4; ++r) {
                        int key = kg0 + 16 * t + 4 * h + r;
                        if (key > qg) st[t][r] = -1e9f;
                    }
            }

            float vmax = st[0][0];
#pragma unroll
            for (int t = 0; t < 4; ++t)
#pragma unroll
                for (int r = 0; r < 4; ++r) vmax = fmaxf(vmax, st[t][r]);
            vmax = fmaxf(vmax, __shfl_xor(vmax, 16));
            vmax = fmaxf(vmax, __shfl_xor(vmax, 32));

            if (!__all(vmax - m <= 8.0f)) {     // defer-max (T13)
                float mn    = fmaxf(m, vmax);
                float alpha = exp2f((m - mn) * L2E);
                l *= alpha;
#pragma unroll
                for (int s4 = 0; s4 < 4; ++s4)
#pragma unroll
                    for (int r = 0; r < 4; ++r) acc[s4][r] *= alpha;
                m = mn;
            }

            float p[4][4];
            float ps = 0.f;
#pragma unroll
            for (int t = 0; t < 4; ++t)
#pragma unroll
                for (int r = 0; r < 4; ++r) {
                    p[t][r] = exp2f((st[t][r] - m) * L2E);
                    ps += p[t][r];
                }
            ps += __shfl_xor(ps, 16);
            ps += __shfl_xor(ps, 32);
            l += ps;

            bf16x8 pf[2];
#pragma unroll
            for (int u = 0; u < 2; ++u) {
                bf16x8 t;
#pragma unroll
                for (int j = 0; j < 8; ++j) t[j] = (short)f2bf(p[2 * u + (j >> 2)][j & 3]);
                pf[u] = t;
            }
#pragma unroll
            for (int s4 = 0; s4 < 4; ++s4)
#pragma unroll
                for (int u = 0; u < 2; ++u) {
                    bf16x4 lo = *(const bf16x4*)(Vd + vswz(c + 16 * s4, 32 * u + 4 * h));
                    bf16x4 hi = *(const bf16x4*)(Vd + vswz(c + 16 * s4, 32 * u + 16 + 4 * h));
                    bf16x8 vf = {lo[0], lo[1], lo[2], lo[3], hi[0], hi[1], hi[2], hi[3]};
                    acc[s4] = __builtin_amdgcn_mfma_f32_16x16x32_bf16(vf, pf[u], acc[s4], 0, 0, 0);
                }
        }

        if (s + 1 < nsteps) {   // write next step into the other buffer
            short* Kd = Kl[(s + 1) & 1];
            short* Vd = Vl[(s + 1) & 1];
#pragma unroll
            for (int i = 0; i < 2; ++i) {
                bf16x4 t;
#pragma unroll
                for (int j = 0; j < 4; ++j) t[j] = (short)f2bf(kr[i][j]);
                *(bf16x4*)(Kd + kswz(skr, sdc + 4 * i)) = t;
            }
#pragma unroll
            for (int j = 0; j < 4; ++j) {
                bf16x2 t;
                t[0] = (short)f2bf(vr[0][j]);
                t[1] = (short)f2bf(vr[1][j]);
                *(bf16x2*)(Vd + vswz(vdc + j, vkr)) = t;
            }
        }
        __syncthreads();
    }

    // ---- epilogue: acc -> LDS (overlays staging; all compute is done)
#pragma unroll
    for (int s4 = 0; s4 < 4; ++s4)
        *(f32x4*)&Ot[R0l + c][16 * s4 + 4 * h] = acc[s4];
    if (h == 0) { Mr[R0l + c] = m; Lr[R0l + c] = l; }
    __syncthreads();

    float* Ogb = Og + ((size_t)b * NQL + Q0) * DVV;

    if (nch == 1) {      // single-chunk tile: finalize directly
        if (tid < 128) invb[tid] = 1.0f / Lr[tid];
        __syncthreads();
#pragma unroll
        for (int j = 0; j < 16; ++j) {
            int f = j * 512 + tid;
            Ogb[f] = Ot[f >> 6][f & 63] * invb[f >> 6];
        }
        return;
    }

    // partial store (coalesced [q][dv] flat), plain stores, no fences
    float* Opg = Op + ((size_t)tile * MAXCH + kc) * (QT * DVV);
#pragma unroll
    for (int j = 0; j < 16; ++j) {
        int f = j * 512 + tid;
        Opg[f] = Ot[f >> 6][f & 63];
    }
    if (tid < 128) {
        Mp[((size_t)tile * MAXCH + kc) * QT + tid] = Mr[tid];
        Lp[((size_t)tile * MAXCH + kc) * QT + tid] = Lr[tid];
    }
}

// ================= Phase 2: combine partials =================
// grid = NB*NQT*4; block (tile, seg): 32 q-rows, all chunks.
__global__ __launch_bounds__(256)
void attn_comb(const float* __restrict__ Op, const float* __restrict__ Mp,
               const float* __restrict__ Lp, float* __restrict__ Og)
{
    const int seg  = blockIdx.x & 3;
    const int tile = blockIdx.x >> 2;
    const int qt   = tile & 15;
    const int b    = tile >> 4;
    const int nch  = (qt + 2) >> 1;
    if (nch == 1) return;                 // finalized in phase 1

    const int tid = threadIdx.x;
    const int r0  = seg * 32;

    __shared__ float scb[MAXCH][32];

    if (tid < 32) {
        const int row = r0 + tid;
        float M = -INFINITY;
        for (int ch = 0; ch < nch; ++ch)
            M = fmaxf(M, Mp[((size_t)tile * MAXCH + ch) * QT + row]);
        float den = 0.f;
        for (int ch = 0; ch < nch; ++ch) {
            float e = exp2f((Mp[((size_t)tile * MAXCH + ch) * QT + row] - M) * L2E);
            den += e * Lp[((size_t)tile * MAXCH + ch) * QT + row];
            scb[ch][tid] = e;
        }
        float iv = 1.0f / den;
        for (int ch = 0; ch < nch; ++ch) scb[ch][tid] *= iv;
    }
    __syncthreads();

    const float* Opt = Op + (size_t)tile * MAXCH * (QT * DVV) + r0 * DVV;
    float* dst = Og + ((size_t)b * NQL + qt * QT + r0) * DVV;
#pragma unroll
    for (int j = 0; j < 8; ++j) {
        int f = j * 256 + tid;
        int row = f >> 6;
        float val = 0.f;
        for (int ch = 0; ch < nch; ++ch)
            val += scb[ch][row] * Opt[(size_t)ch * (QT * DVV) + f];
        dst[f] = val;
    }
}

// ================= fallback (no workspace): round-1 kernel =================
__global__ __launch_bounds__(256, 4)
void attn_fwd_fb(const float* __restrict__ Qg, const float* __restrict__ Kg,
                 const float* __restrict__ Vg, float* __restrict__ Og)
{
    const int tid  = threadIdx.x;
    const int wv   = tid >> 6;
    const int lane = tid & 63;
    const int c    = lane & 15;
    const int h    = lane >> 4;
    const int bid = blockIdx.x;
    const int b   = bid & 7;
    const int qt  = bid >> 3;
    const int q0  = qt << 4;
    const float* Qb = Qg + (size_t)b * NQL * DD;
    const float* Kb = Kg + (size_t)b * NKL * DD;
    const float* Vb = Vg + (size_t)b * NKL * DVV;
    bf16x8 qf[2];
#pragma unroll
    for (int dh = 0; dh < 2; ++dh) {
        const float* src = Qb + (size_t)(q0 + c) * DD + dh * 32 + h * 8;
        f32x4 x0 = *(const f32x4*)(src);
        f32x4 x1 = *(const f32x4*)(src + 4);
        bf16x8 t;
#pragma unroll
        for (int j = 0; j < 4; ++j) {
            t[j]     = (short)f2bf(x0[j] * 0.125f);
            t[4 + j] = (short)f2bf(x1[j] * 0.125f);
        }
        qf[dh] = t;
    }
    float m = -INFINITY, l = 0.0f;
    f32x4 acc[4];
    {
        f32x4 z = {0.f, 0.f, 0.f, 0.f};
#pragma unroll
        for (int s = 0; s < 4; ++s) acc[s] = z;
    }
    const int nkt = (q0 + 47) >> 5;
    for (int kt = wv; kt < nkt; kt += 4) {
        const int kb = kt << 5;
        f32x4 st[2];
        {
            f32x4 z = {0.f, 0.f, 0.f, 0.f};
            st[0] = z; st[1] = z;
        }
#pragma unroll
        for (int t = 0; t < 2; ++t)
#pragma unroll
            for (int dh = 0; dh < 2; ++dh) {
                const float* src = Kb + (size_t)(kb + t * 16 + c) * DD + dh * 32 + h * 8;
                f32x4 x0 = *(const f32x4*)(src);
                f32x4 x1 = *(const f32x4*)(src + 4);
                bf16x8 kf;
#pragma unroll
                for (int j = 0; j < 4; ++j) {
                    kf[j]     = (short)f2bf(x0[j]);
                    kf[4 + j] = (short)f2bf(x1[j]);
                }
                st[t] = __builtin_amdgcn_mfma_f32_16x16x32_bf16(kf, qf[dh], st[t], 0, 0, 0);
            }
        if (kb + 31 > q0) {
#pragma unroll
            for (int t = 0; t < 2; ++t)
#pragma unroll
                for (int r = 0; r < 4; ++r) {
                    int key = kb + t * 16 + h * 4 + r;
                    if (key > q0 + c) st[t][r] = -1e9f;
                }
        }
        float vmax = st[0][0];
#pragma unroll
        for (int t = 0; t < 2; ++t)
#pragma unroll
            for (int r = 0; r < 4; ++r) vmax = fmaxf(vmax, st[t][r]);
        vmax = fmaxf(vmax, __shfl_xor(vmax, 16));
        vmax = fmaxf(vmax, __shfl_xor(vmax, 32));
        float mn    = fmaxf(m, vmax);
        float alpha = exp2f((m - mn) * L2E);
        float p[2][4];
        float ps = 0.f;
#pragma unroll
        for (int t = 0; t < 2; ++t)
#pragma unroll
            for (int r = 0; r < 4; ++r) {
                p[t][r] = exp2f((st[t][r] - mn) * L2E);
                ps += p[t][r];
            }
        ps += __shfl_xor(ps, 16);
        ps += __shfl_xor(ps, 32);
        l = l * alpha + ps;
        m = mn;
#pragma unroll
        for (int s = 0; s < 4; ++s)
#pragma unroll
            for (int r = 0; r < 4; ++r) acc[s][r] *= alpha;
        bf16x8 pf;
#pragma unroll
        for (int j = 0; j < 8; ++j) pf[j] = (short)f2bf(p[j >> 2][j & 3]);
        size_t vrow[8];
#pragma unroll
        for (int j = 0; j < 8; ++j)
            vrow[j] = (size_t)(kb + h * 4 + (j & 3) + ((j >> 2) << 4)) * DVV + c;
#pragma unroll
        for (int s = 0; s < 4; ++s) {
            bf16x8 vf;
#pragma unroll
            for (int j = 0; j < 8; ++j) vf[j] = (short)f2bf(Vb[vrow[j] + s * 16]);
            acc[s] = __builtin_amdgcn_mfma_f32_16x16x32_bf16(vf, pf, acc[s], 0, 0, 0);
        }
    }
    __shared__ float Osc[4][64][17];
    __shared__ float Msc[4][16];
    __shared__ float Lsc[4][16];
#pragma unroll
    for (int s = 0; s < 4; ++s)
#pragma unroll
        for (int r = 0; r < 4; ++r)
            Osc[wv][s * 16 + h * 4 + r][c] = acc[s][r];
    if (lane < 16) { Msc[wv][c] = m; Lsc[wv][c] = l; }
    __syncthreads();
#pragma unroll
    for (int ri = 0; ri < 4; ++ri) {
        const int q = wv * 4 + ri;
        float M = fmaxf(fmaxf(Msc[0][q], Msc[1][q]), fmaxf(Msc[2][q], Msc[3][q]));
        float val = 0.f, den = 0.f;
#pragma unroll
        for (int w2 = 0; w2 < 4; ++w2) {
            float sc = exp2f((Msc[w2][q] - M) * L2E);
            den += Lsc[w2][q] * sc;
            val += Osc[w2][lane][q] * sc;
        }
        Og[((size_t)b * NQL + q0 + q) * DVV + lane] = val / den;
    }
}

extern "C" void kernel_launch(void* const* d_in, const int* in_sizes, int n_in,
                              void* d_out, int out_size, void* d_ws, size_t ws_size,
                              hipStream_t stream)
{
    (void)in_sizes; (void)n_in; (void)out_size;
    const float* Q = (const float*)d_in[0];
    const float* K = (const float*)d_in[1];
    const float* V = (const float*)d_in[2];
    float* O = (float*)d_out;

    // ws layout (floats): Mp | Lp | Op
    const size_t ml_elems = (size_t)(NB * NQT) * MAXCH * QT;        // 131072
    const size_t op_elems = (size_t)(NB * NQT) * MAXCH * QT * DVV;  // 8.4M
    const size_t need = (2 * ml_elems + op_elems) * sizeof(float);

    if (ws_size >= need) {
        float* Mp = (float*)d_ws;
        float* Lp = Mp + ml_elems;
        float* Op = Lp + ml_elems;
        attn_part<<<dim3(NB * NQT * MAXCH), dim3(512), 0, stream>>>(
            Q, K, V, O, Mp, Lp, Op);
        attn_comb<<<dim3(NB * NQT * 4), dim3(256), 0, stream>>>(Op, Mp, Lp, O);
    } else {
        attn_fwd_fb<<<dim3(NB * (NQL / 16)), dim3(256), 0, stream>>>(Q, K, V, O);
    }
}

// Round 6
// 50.218 us; speedup vs baseline: 4.2046x; 1.1228x over previous
//
#include <hip/hip_runtime.h>

#define NB    8
#define NQL   2048
#define NKL   2048
#define DD    64
#define DVV   64
#define QT    64             // q rows per block (4 waves x 16 rows)
#define NQT   32             // NQL/QT
#define CHK   256            // keys per chunk (4 steps of 64)
#define MAXCH 8              // NKL/CHK
#define KSTEP 64

typedef __attribute__((ext_vector_type(8))) short bf16x8;
typedef __attribute__((ext_vector_type(4))) short bf16x4;
typedef __attribute__((ext_vector_type(2))) short bf16x2;
typedef __attribute__((ext_vector_type(4))) float f32x4;

#define L2E 1.44269504088896340736f

__device__ __forceinline__ unsigned short f2bf(float x) {
    union { float f; unsigned u; } v; v.f = x;
    unsigned r = v.u + 0x7FFFu + ((v.u >> 16) & 1u);
    return (unsigned short)(r >> 16);
}

// LDS swizzles (indices in shorts; rows are 64 shorts = 128 B).
__device__ __forceinline__ int kswz(int row, int col) {
    return row * 64 + (col ^ ((row & 7) << 3));
}
__device__ __forceinline__ int vswz(int dv, int col) {
    return dv * 64 + (col ^ ((((dv & 7) ^ ((dv >> 3) & 7))) << 3));
}

// ================= Phase 1: partial flash attention =================
// grid = 1152 (exactly the active units). XCD-aware unit decode:
// bid%8 = XCD x (HW round-robin); XCD x owns {kc=x,b<4} u {kc=7-x,b>=4}
// = 144 units, b-major so consecutive slots share the same K/V chunk
// (2 MB per XCD -> L2-resident staging re-reads).
__global__ __launch_bounds__(256, 4)
void attn_part(const float* __restrict__ Qg, const float* __restrict__ Kg,
               const float* __restrict__ Vg, float* __restrict__ Og,
               float* __restrict__ Mp, float* __restrict__ Lp,
               float* __restrict__ Op)
{
    // ---- unit decode
    const int x    = blockIdx.x & 7;
    const int slot = blockIdx.x >> 3;          // 0..143
    const int a_cnt = 128 - 16 * x;
    int kc, b, qt;
    if (slot < a_cnt) {
        const int w = 32 - 4 * x;
        kc = x;      b = slot / w;           qt = 4 * x + slot % w;
    } else {
        const int s2 = slot - a_cnt;
        const int w = 4 + 4 * x;
        kc = 7 - x;  b = 4 + s2 / w;         qt = 4 * (7 - x) + s2 % w;
    }
    const int nkeys  = QT * (qt + 1);
    const int KC0    = kc * CHK;
    const int nsteps = min(4, (nkeys - KC0) >> 6);     // 1..4
    const int nch    = (qt + 4) >> 2;                  // ceil((qt+1)/4)
    const int tile   = b * NQT + qt;

    const int tid  = threadIdx.x;
    const int wv   = tid >> 6;
    const int lane = tid & 63;
    const int c    = lane & 15;
    const int h    = lane >> 4;
    const int Q0   = qt * QT;
    const int R0l  = 16 * wv;

    const float* Qb = Qg + (size_t)b * NQL * DD;
    const float* Kb = Kg + (size_t)b * NKL * DD;
    const float* Vb = Vg + (size_t)b * NKL * DVV;

    __shared__ short Kl[2][64 * 64];
    __shared__ short Vl[2][64 * 64];

    // staging maps (256 threads; 16 floats K, 16 floats V each)
    const int skr = tid >> 2;             // K row 0..63
    const int sdc = (tid & 3) * 16;       // K col base
    const int vkr = (tid >> 3) << 1;      // V key pair 0..62
    const int vdc = (tid & 7) * 8;        // V dv base 0..56
    f32x4 kr[4], vr[4];

    // Q fragments (B-operand), 1/8 folded. slot (h,j) = Q[row][dh*32+8h+j]
    bf16x8 qf[2];
#pragma unroll
    for (int dh = 0; dh < 2; ++dh) {
        const float* src = Qb + (size_t)(Q0 + R0l + c) * DD + dh * 32 + h * 8;
        f32x4 x0 = *(const f32x4*)(src);
        f32x4 x1 = *(const f32x4*)(src + 4);
        bf16x8 t;
#pragma unroll
        for (int j = 0; j < 4; ++j) {
            t[j]     = (short)f2bf(x0[j] * 0.125f);
            t[4 + j] = (short)f2bf(x1[j] * 0.125f);
        }
        qf[dh] = t;
    }

    // prologue: stage step 0
    {
        const float* kb0 = Kb + (size_t)(KC0 + skr) * DD + sdc;
        kr[0] = *(const f32x4*)(kb0);     kr[1] = *(const f32x4*)(kb0 + 4);
        kr[2] = *(const f32x4*)(kb0 + 8); kr[3] = *(const f32x4*)(kb0 + 12);
        const float* vb0 = Vb + (size_t)(KC0 + vkr) * DVV + vdc;
        vr[0] = *(const f32x4*)(vb0);       vr[1] = *(const f32x4*)(vb0 + 4);
        vr[2] = *(const f32x4*)(vb0 + DVV); vr[3] = *(const f32x4*)(vb0 + DVV + 4);
        short* Kd = Kl[0]; short* Vd = Vl[0];
#pragma unroll
        for (int i = 0; i < 4; ++i) {
            bf16x4 t;
#pragma unroll
            for (int j = 0; j < 4; ++j) t[j] = (short)f2bf(kr[i][j]);
            *(bf16x4*)(Kd + kswz(skr, sdc + 4 * i)) = t;
        }
#pragma unroll
        for (int j = 0; j < 8; ++j) {
            bf16x2 t;
            t[0] = (short)f2bf(vr[j >> 2][j & 3]);
            t[1] = (short)f2bf(vr[2 + (j >> 2)][j & 3]);
            *(bf16x2*)(Vd + vswz(vdc + j, vkr)) = t;
        }
    }
    __syncthreads();

    float m = -INFINITY, l = 0.0f;
    f32x4 acc[4];
    {
        f32x4 z = {0.f, 0.f, 0.f, 0.f};
#pragma unroll
        for (int s4 = 0; s4 < 4; ++s4) acc[s4] = z;
    }

    for (int s = 0; s < nsteps; ++s) {
        const int pb = s & 1;

        if (s + 1 < nsteps) {   // T14: issue next step's global loads early
            const float* kb0 = Kb + (size_t)(KC0 + (s + 1) * KSTEP + skr) * DD + sdc;
            kr[0] = *(const f32x4*)(kb0);     kr[1] = *(const f32x4*)(kb0 + 4);
            kr[2] = *(const f32x4*)(kb0 + 8); kr[3] = *(const f32x4*)(kb0 + 12);
            const float* vb0 = Vb + (size_t)(KC0 + (s + 1) * KSTEP + vkr) * DVV + vdc;
            vr[0] = *(const f32x4*)(vb0);       vr[1] = *(const f32x4*)(vb0 + 4);
            vr[2] = *(const f32x4*)(vb0 + DVV); vr[3] = *(const f32x4*)(vb0 + DVV + 4);
        }

        const int kg0 = KC0 + s * KSTEP;
        if (kg0 <= Q0 + R0l + 15) {            // wave-active (wave-uniform)
            const short* Kd = Kl[pb];
            const short* Vd = Vl[pb];

            f32x4 st[4];
            {
                f32x4 z = {0.f, 0.f, 0.f, 0.f};
#pragma unroll
                for (int t = 0; t < 4; ++t) st[t] = z;
            }
#pragma unroll
            for (int t = 0; t < 4; ++t)
#pragma unroll
                for (int dh = 0; dh < 2; ++dh) {
                    bf16x8 kf = *(const bf16x8*)(Kd + kswz(16 * t + c, dh * 32 + h * 8));
                    st[t] = __builtin_amdgcn_mfma_f32_16x16x32_bf16(kf, qf[dh], st[t], 0, 0, 0);
                }

            if (kg0 + KSTEP - 1 > Q0 + R0l) {   // diagonal step: mask
                const int qg = Q0 + R0l + c;
#pragma unroll
                for (int t = 0; t < 4; ++t)
#pragma unroll
                    for (int r = 0; r < 4; ++r) {
                        int key = kg0 + 16 * t + 4 * h + r;
                        if (key > qg) st[t][r] = -1e9f;
                    }
            }

            float vmax = st[0][0];
#pragma unroll
            for (int t = 0; t < 4; ++t)
#pragma unroll
                for (int r = 0; r < 4; ++r) vmax = fmaxf(vmax, st[t][r]);
            vmax = fmaxf(vmax, __shfl_xor(vmax, 16));
            vmax = fmaxf(vmax, __shfl_xor(vmax, 32));

            if (!__all(vmax - m <= 8.0f)) {     // defer-max (T13)
                float mn    = fmaxf(m, vmax);
                float alpha = exp2f((m - mn) * L2E);
                l *= alpha;
#pragma unroll
                for (int s4 = 0; s4 < 4; ++s4)
#pragma unroll
                    for (int r = 0; r < 4; ++r) acc[s4][r] *= alpha;
                m = mn;
            }

            float p[4][4];
            float ps = 0.f;
#pragma unroll
            for (int t = 0; t < 4; ++t)
#pragma unroll
                for (int r = 0; r < 4; ++r) {
                    p[t][r] = exp2f((st[t][r] - m) * L2E);
                    ps += p[t][r];
                }
            ps += __shfl_xor(ps, 16);
            ps += __shfl_xor(ps, 32);
            l += ps;

            bf16x8 pf[2];
#pragma unroll
            for (int u = 0; u < 2; ++u) {
                bf16x8 t;
#pragma unroll
                for (int j = 0; j < 8; ++j) t[j] = (short)f2bf(p[2 * u + (j >> 2)][j & 3]);
                pf[u] = t;
            }
#pragma unroll
            for (int s4 = 0; s4 < 4; ++s4)
#pragma unroll
                for (int u = 0; u < 2; ++u) {
                    bf16x4 lo = *(const bf16x4*)(Vd + vswz(c + 16 * s4, 32 * u + 4 * h));
                    bf16x4 hi = *(const bf16x4*)(Vd + vswz(c + 16 * s4, 32 * u + 16 + 4 * h));
                    bf16x8 vf = {lo[0], lo[1], lo[2], lo[3], hi[0], hi[1], hi[2], hi[3]};
                    acc[s4] = __builtin_amdgcn_mfma_f32_16x16x32_bf16(vf, pf[u], acc[s4], 0, 0, 0);
                }
        }

        if (s + 1 < nsteps) {   // write next step into the other buffer
            short* Kd = Kl[(s + 1) & 1];
            short* Vd = Vl[(s + 1) & 1];
#pragma unroll
            for (int i = 0; i < 4; ++i) {
                bf16x4 t;
#pragma unroll
                for (int j = 0; j < 4; ++j) t[j] = (short)f2bf(kr[i][j]);
                *(bf16x4*)(Kd + kswz(skr, sdc + 4 * i)) = t;
            }
#pragma unroll
            for (int j = 0; j < 8; ++j) {
                bf16x2 t;
                t[0] = (short)f2bf(vr[j >> 2][j & 3]);
                t[1] = (short)f2bf(vr[2 + (j >> 2)][j & 3]);
                *(bf16x2*)(Vd + vswz(vdc + j, vkr)) = t;
            }
        }
        __syncthreads();
    }

    // ---- epilogue
    const int q = R0l + c;                      // local q row
    if (nch == 1) {                             // complete: finalize directly
        const float iv = 1.0f / l;
        float* dst = Og + ((size_t)b * NQL + Q0 + q) * DVV;
#pragma unroll
        for (int s4 = 0; s4 < 4; ++s4) {
            f32x4 t = acc[s4];
#pragma unroll
            for (int r = 0; r < 4; ++r) t[r] *= iv;
            *(f32x4*)(dst + 16 * s4 + 4 * h) = t;
        }
        return;
    }

    // partial store: Op[(tile*MAXCH+kc)][q][dv] (vector stores)
    float* Opg = Op + ((size_t)tile * MAXCH + kc) * (QT * DVV);
#pragma unroll
    for (int s4 = 0; s4 < 4; ++s4)
        *(f32x4*)(Opg + (size_t)q * DVV + 16 * s4 + 4 * h) = acc[s4];
    if (h == 0) {
        Mp[((size_t)tile * MAXCH + kc) * QT + q] = m;
        Lp[((size_t)tile * MAXCH + kc) * QT + q] = l;
    }
}

// ================= Phase 2: combine partials =================
// grid = NB*NQT*2; block (tile, seg): 32 q-rows, all chunks. Skips nch==1.
__global__ __launch_bounds__(256)
void attn_comb(const float* __restrict__ Op, const float* __restrict__ Mp,
               const float* __restrict__ Lp, float* __restrict__ Og)
{
    const int seg  = blockIdx.x & 1;
    const int tile = blockIdx.x >> 1;
    const int qt   = tile & (NQT - 1);
    const int b    = tile >> 5;
    const int nch  = (qt + 4) >> 2;
    if (nch == 1) return;                 // finalized in phase 1

    const int tid = threadIdx.x;
    const int r0  = seg * 32;

    __shared__ float scb[MAXCH][32];

    if (tid < 32) {
        const int row = r0 + tid;
        float M = -INFINITY;
        for (int ch = 0; ch < nch; ++ch)
            M = fmaxf(M, Mp[((size_t)tile * MAXCH + ch) * QT + row]);
        float den = 0.f;
        for (int ch = 0; ch < nch; ++ch) {
            float e = exp2f((Mp[((size_t)tile * MAXCH + ch) * QT + row] - M) * L2E);
            den += e * Lp[((size_t)tile * MAXCH + ch) * QT + row];
            scb[ch][tid] = e;
        }
        float iv = 1.0f / den;
        for (int ch = 0; ch < nch; ++ch) scb[ch][tid] *= iv;
    }
    __syncthreads();

    const float* Opt = Op + (size_t)tile * MAXCH * (QT * DVV) + (size_t)r0 * DVV;
    float* dst = Og + ((size_t)b * NQL + qt * QT + r0) * DVV;
#pragma unroll
    for (int j = 0; j < 8; ++j) {
        int f = j * 256 + tid;
        int row = f >> 6;
        float val = 0.f;
        for (int ch = 0; ch < nch; ++ch)
            val += scb[ch][row] * Opt[(size_t)ch * (QT * DVV) + f];
        dst[f] = val;
    }
}

// ================= fallback (no workspace): round-1 kernel =================
__global__ __launch_bounds__(256, 4)
void attn_fwd_fb(const float* __restrict__ Qg, const float* __restrict__ Kg,
                 const float* __restrict__ Vg, float* __restrict__ Og)
{
    const int tid  = threadIdx.x;
    const int wv   = tid >> 6;
    const int lane = tid & 63;
    const int c    = lane & 15;
    const int h    = lane >> 4;
    const int bid = blockIdx.x;
    const int b   = bid & 7;
    const int qt  = bid >> 3;
    const int q0  = qt << 4;
    const float* Qb = Qg + (size_t)b * NQL * DD;
    const float* Kb = Kg + (size_t)b * NKL * DD;
    const float* Vb = Vg + (size_t)b * NKL * DVV;
    bf16x8 qf[2];
#pragma unroll
    for (int dh = 0; dh < 2; ++dh) {
        const float* src = Qb + (size_t)(q0 + c) * DD + dh * 32 + h * 8;
        f32x4 x0 = *(const f32x4*)(src);
        f32x4 x1 = *(const f32x4*)(src + 4);
        bf16x8 t;
#pragma unroll
        for (int j = 0; j < 4; ++j) {
            t[j]     = (short)f2bf(x0[j] * 0.125f);
            t[4 + j] = (short)f2bf(x1[j] * 0.125f);
        }
        qf[dh] = t;
    }
    float m = -INFINITY, l = 0.0f;
    f32x4 acc[4];
    {
        f32x4 z = {0.f, 0.f, 0.f, 0.f};
#pragma unroll
        for (int s = 0; s < 4; ++s) acc[s] = z;
    }
    const int nkt = (q0 + 47) >> 5;
    for (int kt = wv; kt < nkt; kt += 4) {
        const int kb = kt << 5;
        f32x4 st[2];
        {
            f32x4 z = {0.f, 0.f, 0.f, 0.f};
            st[0] = z; st[1] = z;
        }
#pragma unroll
        for (int t = 0; t < 2; ++t)
#pragma unroll
            for (int dh = 0; dh < 2; ++dh) {
                const float* src = Kb + (size_t)(kb + t * 16 + c) * DD + dh * 32 + h * 8;
                f32x4 x0 = *(const f32x4*)(src);
                f32x4 x1 = *(const f32x4*)(src + 4);
                bf16x8 kf;
#pragma unroll
                for (int j = 0; j < 4; ++j) {
                    kf[j]     = (short)f2bf(x0[j]);
                    kf[4 + j] = (short)f2bf(x1[j]);
                }
                st[t] = __builtin_amdgcn_mfma_f32_16x16x32_bf16(kf, qf[dh], st[t], 0, 0, 0);
            }
        if (kb + 31 > q0) {
#pragma unroll
            for (int t = 0; t < 2; ++t)
#pragma unroll
                for (int r = 0; r < 4; ++r) {
                    int key = kb + t * 16 + h * 4 + r;
                    if (key > q0 + c) st[t][r] = -1e9f;
                }
        }
        float vmax = st[0][0];
#pragma unroll
        for (int t = 0; t < 2; ++t)
#pragma unroll
            for (int r = 0; r < 4; ++r) vmax = fmaxf(vmax, st[t][r]);
        vmax = fmaxf(vmax, __shfl_xor(vmax, 16));
        vmax = fmaxf(vmax, __shfl_xor(vmax, 32));
        float mn    = fmaxf(m, vmax);
        float alpha = exp2f((m - mn) * L2E);
        float p[2][4];
        float ps = 0.f;
#pragma unroll
        for (int t = 0; t < 2; ++t)
#pragma unroll
            for (int r = 0; r < 4; ++r) {
                p[t][r] = exp2f((st[t][r] - mn) * L2E);
                ps += p[t][r];
            }
        ps += __shfl_xor(ps, 16);
        ps += __shfl_xor(ps, 32);
        l = l * alpha + ps;
        m = mn;
#pragma unroll
        for (int s = 0; s < 4; ++s)
#pragma unroll
            for (int r = 0; r < 4; ++r) acc[s][r] *= alpha;
        bf16x8 pf;
#pragma unroll
        for (int j = 0; j < 8; ++j) pf[j] = (short)f2bf(p[j >> 2][j & 3]);
        size_t vrow[8];
#pragma unroll
        for (int j = 0; j < 8; ++j)
            vrow[j] = (size_t)(kb + h * 4 + (j & 3) + ((j >> 2) << 4)) * DVV + c;
#pragma unroll
        for (int s = 0; s < 4; ++s) {
            bf16x8 vf;
#pragma unroll
            for (int j = 0; j < 8; ++j) vf[j] = (short)f2bf(Vb[vrow[j] + s * 16]);
            acc[s] = __builtin_amdgcn_mfma_f32_16x16x32_bf16(vf, pf, acc[s], 0, 0, 0);
        }
    }
    __shared__ float Osc[4][64][17];
    __shared__ float Msc[4][16];
    __shared__ float Lsc[4][16];
#pragma unroll
    for (int s = 0; s < 4; ++s)
#pragma unroll
        for (int r = 0; r < 4; ++r)
            Osc[wv][s * 16 + h * 4 + r][c] = acc[s][r];
    if (lane < 16) { Msc[wv][c] = m; Lsc[wv][c] = l; }
    __syncthreads();
#pragma unroll
    for (int ri = 0; ri < 4; ++ri) {
        const int q = wv * 4 + ri;
        float M = fmaxf(fmaxf(Msc[0][q], Msc[1][q]), fmaxf(Msc[2][q], Msc[3][q]));
        float val = 0.f, den = 0.f;
#pragma unroll
        for (int w2 = 0; w2 < 4; ++w2) {
            float sc = exp2f((Msc[w2][q] - M) * L2E);
            den += Lsc[w2][q] * sc;
            val += Osc[w2][lane][q] * sc;
        }
        Og[((size_t)b * NQL + q0 + q) * DVV + lane] = val / den;
    }
}

extern "C" void kernel_launch(void* const* d_in, const int* in_sizes, int n_in,
                              void* d_out, int out_size, void* d_ws, size_t ws_size,
                              hipStream_t stream)
{
    (void)in_sizes; (void)n_in; (void)out_size;
    const float* Q = (const float*)d_in[0];
    const float* K = (const float*)d_in[1];
    const float* V = (const float*)d_in[2];
    float* O = (float*)d_out;

    // ws layout (floats): Mp | Lp | Op
    const size_t ml_elems = (size_t)(NB * NQT) * MAXCH * QT;
    const size_t op_elems = (size_t)(NB * NQT) * MAXCH * QT * DVV;
    const size_t need = (2 * ml_elems + op_elems) * sizeof(float);

    if (ws_size >= need) {
        float* Mp = (float*)d_ws;
        float* Lp = Mp + ml_elems;
        float* Op = Lp + ml_elems;
        attn_part<<<dim3(1152), dim3(256), 0, stream>>>(Q, K, V, O, Mp, Lp, Op);
        attn_comb<<<dim3(NB * NQT * 2), dim3(256), 0, stream>>>(Op, Mp, Lp, O);
    } else {
        attn_fwd_fb<<<dim3(NB * (NQL / 16)), dim3(256), 0, stream>>>(Q, K, V, O);
    }
}